// Round 10
// baseline (155.662 us; speedup 1.0000x reference)
//
#include <hip/hip_runtime.h>
#include <math.h>

#define D 256
#define NRULES 1024
#define TPB 8     // tokens per pass over a rule matrix
#define KMAX 16   // bucket stride; slot>=KMAX spills (P ~ 0 at Poisson(2))
#define NSPILLBLK 64

// ---------------- prep: parallel histogram, no scan ----------------
__global__ void prep_kernel(const int* __restrict__ token_ids,
                            const int* __restrict__ token_rules,
                            int ntok,
                            int* __restrict__ counts,     // [NRULES] pre-zeroed
                            int* __restrict__ bucket,     // [NRULES*KMAX]
                            int* __restrict__ spill_tok,  // [ntok]
                            int* __restrict__ spill_rule, // [ntok]
                            int* __restrict__ nspill) {   // [1] pre-zeroed
    const int i = blockIdx.x * blockDim.x + threadIdx.x;
    if (i >= ntok) return;
    const int r = token_rules[token_ids[i]];
    const int slot = atomicAdd(&counts[r], 1);
    if (slot < KMAX) {
        bucket[r * KMAX + slot] = i;
    } else {
        const int k = atomicAdd(nspill, 1);
        spill_tok[k]  = i;
        spill_rule[k] = r;
    }
}

// ---------------- one TPB-pass over a rule matrix ----------------
// 4 waves; wave owns 64-col quarter; rr=lane>>4 row subgroup (rows 4i+rr).
// 8-deep register prefetch of M issued BEFORE the h-stage barrier.
template <int CR>
__device__ __forceinline__ void rule_pass(
    const float* __restrict__ M,
    const float* __restrict__ hidden,
    const int*   __restrict__ gtoks,   // global: bucket row or spill_tok+k
    int base, int c,                   // live tokens this pass, c <= CR
    bool trailing_barrier,
    int wave, int lane, int rr, int col,
    float (*__restrict__ h_lds)[D], float* __restrict__ sq_lds,
    float* __restrict__ out)
{
    // prefetch first 8 iterations' M segments (independent of h staging)
    float4 pf[8];
    #pragma unroll
    for (int k = 0; k < 8; ++k)
        pf[k] = *reinterpret_cast<const float4*>(
            M + (size_t)((k << 2) + rr) * D + col);

    // stage h rows as float4: wave j stages token row j (64 lanes x 16B = 1KB)
    for (int j = wave; j < CR; j += 4) {
        float4 v = {0.f, 0.f, 0.f, 0.f};
        if (j < c)
            v = *reinterpret_cast<const float4*>(
                &hidden[(size_t)gtoks[base + j] * D + (lane << 2)]);
        *reinterpret_cast<float4*>(&h_lds[j][lane << 2]) = v;
    }
    __syncthreads();

    float4 acc[CR];
    #pragma unroll
    for (int j = 0; j < CR; ++j) acc[j] = float4{0.f, 0.f, 0.f, 0.f};
    float s0 = 0.f, s1 = 0.f, s2 = 0.f, s3 = 0.f;  // 4 fro chains

    for (int g = 0; g < 8; ++g) {               // 8 groups x 8 iters = 64 rows/lane
        const float* __restrict__ Mg = M + (size_t)(g << 5) * D;
        #pragma unroll
        for (int k = 0; k < 8; ++k) {
            const float4 m = pf[k];
            if (g < 7)                           // rolling 8-deep prefetch
                pf[k] = *reinterpret_cast<const float4*>(
                    Mg + (size_t)(32 + (k << 2) + rr) * D + col);
            s0 = fmaf(m.x, m.x, s0);
            s1 = fmaf(m.y, m.y, s1);
            s2 = fmaf(m.z, m.z, s2);
            s3 = fmaf(m.w, m.w, s3);
            const int d = (g << 5) + (k << 2) + rr;
            #pragma unroll
            for (int j = 0; j < CR; ++j) {
                const float h = h_lds[j][d];     // 4 addrs/wave, x16 broadcast
                acc[j].x = fmaf(h, m.x, acc[j].x);
                acc[j].y = fmaf(h, m.y, acc[j].y);
                acc[j].z = fmaf(h, m.z, acc[j].z);
                acc[j].w = fmaf(h, m.w, acc[j].w);
            }
        }
    }

    // Frobenius: wave reduce, park per wave
    float sq = (s0 + s1) + (s2 + s3);
    #pragma unroll
    for (int off = 32; off > 0; off >>= 1)
        sq += __shfl_down(sq, off, 64);
    if (lane == 0) sq_lds[wave] = sq;

    // butterfly over the 4 row-subgroups: every lane gets full column sums
    #pragma unroll
    for (int j = 0; j < CR; ++j) {
        #pragma unroll
        for (int mask = 16; mask < 64; mask <<= 1) {
            acc[j].x += __shfl_xor(acc[j].x, mask, 64);
            acc[j].y += __shfl_xor(acc[j].y, mask, 64);
            acc[j].z += __shfl_xor(acc[j].z, mask, 64);
            acc[j].w += __shfl_xor(acc[j].w, mask, 64);
        }
    }
    __syncthreads();  // sq_lds visible to all

    const float fro2 = sq_lds[0] + sq_lds[1] + sq_lds[2] + sq_lds[3];
    const float inv  = 1.0f / fmaxf(sqrtf(fro2), 1e-12f);

    // subgroup (j&3) writes token j's quarter (16 lanes x 16B contiguous)
    #pragma unroll
    for (int j = 0; j < CR; ++j) {
        if (j < c && rr == (j & 3)) {
            const int tok = gtoks[base + j];
            float4 o;
            o.x = acc[j].x * inv; o.y = acc[j].y * inv;
            o.z = acc[j].z * inv; o.w = acc[j].w * inv;
            *reinterpret_cast<float4*>(&out[(size_t)tok * D + col]) = o;
        }
    }
    if (trailing_barrier) __syncthreads();  // protect h_lds/sq_lds for next pass
}

// ---------------- process: block b == rule b ----------------
__global__ __launch_bounds__(256) void process_kernel(
    const float* __restrict__ hidden,     // [NTOK, D]
    const float* __restrict__ rules,      // [NRULES, D, D]
    const int*   __restrict__ counts,
    const int*   __restrict__ bucket,
    const int*   __restrict__ spill_tok,
    const int*   __restrict__ spill_rule,
    const int*   __restrict__ nspill,
    float* __restrict__ out)
{
    const int b    = blockIdx.x;
    const int t    = threadIdx.x;
    const int wave = t >> 6;
    const int lane = t & 63;
    const int rr   = lane >> 4;
    const int col  = (wave << 6) + ((lane & 15) << 2);

    __shared__ float h_lds[TPB][D];
    __shared__ float sq_lds[4];

    if (b < NRULES) {
        const int cnt = min(counts[b], KMAX);
        if (cnt > 0) {
            const float* __restrict__ M = rules + (size_t)b * D * D;
            const int* __restrict__ gt = bucket + b * KMAX;
            for (int base = 0; base < cnt; base += TPB) {
                const int c = min(cnt - base, TPB);
                const bool more = (base + TPB < cnt);
                switch ((c == 1) ? 1 : (c == 2) ? 2 : (c <= 4) ? 4 : 8) {
                    case 1:  rule_pass<1>(M, hidden, gt, base, c, more, wave, lane, rr, col, h_lds, sq_lds, out); break;
                    case 2:  rule_pass<2>(M, hidden, gt, base, c, more, wave, lane, rr, col, h_lds, sq_lds, out); break;
                    case 4:  rule_pass<4>(M, hidden, gt, base, c, more, wave, lane, rr, col, h_lds, sq_lds, out); break;
                    default: rule_pass<8>(M, hidden, gt, base, c, more, wave, lane, rr, col, h_lds, sq_lds, out); break;
                }
            }
        }
    }

    // rare overflow tokens (count>KMAX): strided over all blocks, 1-token passes
    const int ns = nspill[0];
    for (int k = b; k < ns; k += gridDim.x) {
        __syncthreads();  // protect h_lds from any prior pass
        rule_pass<1>(rules + (size_t)spill_rule[k] * D * D, hidden,
                     spill_tok + k, 0, 1, false,
                     wave, lane, rr, col, h_lds, sq_lds, out);
    }
}

// ---------------- launcher ----------------
extern "C" void kernel_launch(void* const* d_in, const int* in_sizes, int n_in,
                              void* d_out, int out_size, void* d_ws, size_t ws_size,
                              hipStream_t stream) {
    const float* hidden      = (const float*)d_in[0];
    const int*   token_ids   = (const int*)d_in[1];
    const float* rules       = (const float*)d_in[2];
    const int*   token_rules = (const int*)d_in[3];
    float*       out         = (float*)d_out;

    const int ntok = in_sizes[1];  // B*S

    int* ws         = (int*)d_ws;
    int* counts     = ws;                        // NRULES
    int* nspill     = ws + NRULES;               // 1 (padded to 8)
    int* bucket     = ws + NRULES + 8;           // NRULES*KMAX
    int* spill_tok  = bucket + NRULES * KMAX;    // ntok
    int* spill_rule = spill_tok + ntok;          // ntok

    hipMemsetAsync(counts, 0, (NRULES + 8) * sizeof(int), stream);
    prep_kernel<<<(ntok + 255) / 256, 256, 0, stream>>>(
        token_ids, token_rules, ntok, counts, bucket, spill_tok, spill_rule, nspill);
    process_kernel<<<NRULES + NSPILLBLK, 256, 0, stream>>>(
        hidden, rules, counts, bucket, spill_tok, spill_rule, nspill, out);
}

// Round 11
// 57.116 us; speedup vs baseline: 2.7253x; 2.7253x over previous
//
#include <hip/hip_runtime.h>
#include <math.h>

#define D 256
#define NRULES 1024
#define TPB 8     // tokens per pass over a rule matrix
#define KMAX 16   // bucket stride; slot>=KMAX spills (P ~ 0 at Poisson(2))
#define NSPILLBLK 64

// ---------------- prep: parallel histogram, no scan ----------------
__global__ void prep_kernel(const int* __restrict__ token_ids,
                            const int* __restrict__ token_rules,
                            int ntok,
                            int* __restrict__ counts,     // [NRULES] pre-zeroed
                            int* __restrict__ bucket,     // [NRULES*KMAX]
                            int* __restrict__ spill_tok,  // [ntok]
                            int* __restrict__ spill_rule, // [ntok]
                            int* __restrict__ nspill) {   // [1] pre-zeroed
    const int i = blockIdx.x * blockDim.x + threadIdx.x;
    if (i >= ntok) return;
    const int r = token_rules[token_ids[i]];
    const int slot = atomicAdd(&counts[r], 1);
    if (slot < KMAX) {
        bucket[r * KMAX + slot] = i;
    } else {
        const int k = atomicAdd(nspill, 1);
        spill_tok[k]  = i;
        spill_rule[k] = r;
    }
}

// ---------------- one TPB-pass, 8 waves over one rule matrix ----------------
// Wave w: h=w>>2 row-half-phase, p=w&3 col quarter. Lane: rr=lane>>4, cc=lane&15.
// Wave (h,p) reads rows d = 8i + 4h + rr, cols [64p+4cc, +4). Step i: the 8
// waves consume rows 8i..8i+7 fully (8KB contiguous) — block-local stream.
template <int CR>
__device__ __forceinline__ void rule_pass(
    const float* __restrict__ M,
    const float* __restrict__ hidden,
    const int*   __restrict__ gtoks,   // global: bucket row or spill_tok+k
    int base, int c,                   // live tokens this pass, c <= CR
    bool trailing_barrier,
    int wave, int lane, int hh, int rr, int col,
    float (*__restrict__ h_lds)[D], float (*__restrict__ y_lds)[D],
    float* __restrict__ sq_lds,
    float* __restrict__ out)
{
    // stage h rows as float4: wave j stages token row j (64 lanes x 16B = 1KB)
    for (int j = wave; j < CR; j += 8) {
        float4 v = {0.f, 0.f, 0.f, 0.f};
        if (j < c)
            v = *reinterpret_cast<const float4*>(
                &hidden[(size_t)gtoks[base + j] * D + (lane << 2)]);
        *reinterpret_cast<float4*>(&h_lds[j][lane << 2]) = v;
    }
    __syncthreads();

    float4 acc[CR];
    #pragma unroll
    for (int j = 0; j < CR; ++j) acc[j] = float4{0.f, 0.f, 0.f, 0.f};
    float s0 = 0.f, s1 = 0.f, s2 = 0.f, s3 = 0.f;  // independent fro chains

    const int dbase = (hh << 2) + rr;
    #pragma unroll 8
    for (int i = 0; i < 32; ++i) {
        const int d = (i << 3) + dbase;
        const float4 m = *reinterpret_cast<const float4*>(M + (size_t)d * D + col);
        s0 = fmaf(m.x, m.x, s0);
        s1 = fmaf(m.y, m.y, s1);
        s2 = fmaf(m.z, m.z, s2);
        s3 = fmaf(m.w, m.w, s3);
        #pragma unroll
        for (int j = 0; j < CR; ++j) {
            const float h = h_lds[j][d];  // 4 addrs/wave, x16 broadcast — conflict-free
            acc[j].x = fmaf(h, m.x, acc[j].x);
            acc[j].y = fmaf(h, m.y, acc[j].y);
            acc[j].z = fmaf(h, m.z, acc[j].z);
            acc[j].w = fmaf(h, m.w, acc[j].w);
        }
    }

    // Frobenius: wave reduce, park per wave (8 partials)
    float sq = (s0 + s1) + (s2 + s3);
    #pragma unroll
    for (int off = 32; off > 0; off >>= 1)
        sq += __shfl_down(sq, off, 64);
    if (lane == 0) sq_lds[wave] = sq;

    // butterfly over the 4 row-subgroups: lane gets its wave's 64-row sums
    #pragma unroll
    for (int j = 0; j < CR; ++j) {
        #pragma unroll
        for (int mask = 16; mask < 64; mask <<= 1) {
            acc[j].x += __shfl_xor(acc[j].x, mask, 64);
            acc[j].y += __shfl_xor(acc[j].y, mask, 64);
            acc[j].z += __shfl_xor(acc[j].z, mask, 64);
            acc[j].w += __shfl_xor(acc[j].w, mask, 64);
        }
    }

    // half h=1 parks its partial y; half h=0 combines, normalizes, stores
    if (hh == 1) {
        #pragma unroll
        for (int j = 0; j < CR; ++j)
            if (rr == (j & 3))
                *reinterpret_cast<float4*>(&y_lds[j][col]) = acc[j];
    }
    __syncthreads();

    if (hh == 0) {
        const float fro2 = ((sq_lds[0] + sq_lds[1]) + (sq_lds[2] + sq_lds[3])) +
                           ((sq_lds[4] + sq_lds[5]) + (sq_lds[6] + sq_lds[7]));
        const float inv = 1.0f / fmaxf(sqrtf(fro2), 1e-12f);
        #pragma unroll
        for (int j = 0; j < CR; ++j) {
            if (j < c && rr == (j & 3)) {
                const float4 o = *reinterpret_cast<const float4*>(&y_lds[j][col]);
                float4 v;
                v.x = (acc[j].x + o.x) * inv; v.y = (acc[j].y + o.y) * inv;
                v.z = (acc[j].z + o.z) * inv; v.w = (acc[j].w + o.w) * inv;
                *reinterpret_cast<float4*>(&out[(size_t)gtoks[base + j] * D + col]) = v;
            }
        }
    }
    if (trailing_barrier) __syncthreads();  // protect h_lds/y_lds for next pass
}

// ---------------- process: block b == rule b, 8 waves ----------------
__global__ __launch_bounds__(512) void process_kernel(
    const float* __restrict__ hidden,     // [NTOK, D]
    const float* __restrict__ rules,      // [NRULES, D, D]
    const int*   __restrict__ counts,
    const int*   __restrict__ bucket,
    const int*   __restrict__ spill_tok,
    const int*   __restrict__ spill_rule,
    const int*   __restrict__ nspill,
    float* __restrict__ out)
{
    const int b    = blockIdx.x;
    const int t    = threadIdx.x;
    const int wave = t >> 6;
    const int lane = t & 63;
    const int hh   = wave >> 2;
    const int rr   = lane >> 4;
    const int col  = ((wave & 3) << 6) + ((lane & 15) << 2);

    __shared__ float h_lds[TPB][D];
    __shared__ float y_lds[TPB][D];
    __shared__ float sq_lds[8];

    if (b < NRULES) {
        const int cnt = min(counts[b], KMAX);
        if (cnt > 0) {
            const float* __restrict__ M = rules + (size_t)b * D * D;
            const int* __restrict__ gt = bucket + b * KMAX;
            for (int base = 0; base < cnt; base += TPB) {
                const int c = min(cnt - base, TPB);
                const bool more = (base + TPB < cnt);
                switch ((c == 1) ? 1 : (c == 2) ? 2 : (c <= 4) ? 4 : 8) {
                    case 1:  rule_pass<1>(M, hidden, gt, base, c, more, wave, lane, hh, rr, col, h_lds, y_lds, sq_lds, out); break;
                    case 2:  rule_pass<2>(M, hidden, gt, base, c, more, wave, lane, hh, rr, col, h_lds, y_lds, sq_lds, out); break;
                    case 4:  rule_pass<4>(M, hidden, gt, base, c, more, wave, lane, hh, rr, col, h_lds, y_lds, sq_lds, out); break;
                    default: rule_pass<8>(M, hidden, gt, base, c, more, wave, lane, hh, rr, col, h_lds, y_lds, sq_lds, out); break;
                }
            }
        }
    }

    // rare overflow tokens (count>KMAX): strided over all blocks, 1-token passes
    const int ns = nspill[0];
    for (int k = b; k < ns; k += gridDim.x) {
        __syncthreads();  // protect h_lds/y_lds from any prior pass
        rule_pass<1>(rules + (size_t)spill_rule[k] * D * D, hidden,
                     spill_tok + k, 0, 1, false,
                     wave, lane, hh, rr, col, h_lds, y_lds, sq_lds, out);
    }
}

// ---------------- launcher ----------------
extern "C" void kernel_launch(void* const* d_in, const int* in_sizes, int n_in,
                              void* d_out, int out_size, void* d_ws, size_t ws_size,
                              hipStream_t stream) {
    const float* hidden      = (const float*)d_in[0];
    const int*   token_ids   = (const int*)d_in[1];
    const float* rules       = (const float*)d_in[2];
    const int*   token_rules = (const int*)d_in[3];
    float*       out         = (float*)d_out;

    const int ntok = in_sizes[1];  // B*S

    int* ws         = (int*)d_ws;
    int* counts     = ws;                        // NRULES
    int* nspill     = ws + NRULES;               // 1 (padded to 8)
    int* bucket     = ws + NRULES + 8;           // NRULES*KMAX
    int* spill_tok  = bucket + NRULES * KMAX;    // ntok
    int* spill_rule = spill_tok + ntok;          // ntok

    hipMemsetAsync(counts, 0, (NRULES + 8) * sizeof(int), stream);
    prep_kernel<<<(ntok + 255) / 256, 256, 0, stream>>>(
        token_ids, token_rules, ntok, counts, bucket, spill_tok, spill_rule, nspill);
    process_kernel<<<NRULES + NSPILLBLK, 512, 0, stream>>>(
        hidden, rules, counts, bucket, spill_tok, spill_rule, nspill, out);
}